// Round 8
// baseline (389.712 us; speedup 1.0000x reference)
//
#include <hip/hip_runtime.h>
#include <math.h>

#define B_ 2
#define L_ 5000
#define E_ 20
#define H_ 5
#define FF_ 120
#define DEC_ 40
#define K_ 50
#define PAD_ 25
#define SCALE 0.22360679774997896f  // 1/sqrt(E)

#define NM 35                    // symmetric monomials deg<=3 in 4 vars
#define MST2 180                 // per-(b,h): 5 c-slots x 36 (35 used + pad)
#define MLAYER (B_ * H_ * MST2)  // 1800 floats per layer
#define ACH 128                  // keys per moment block
#define NCH 40                   // chunks per (b,h)
#define GX 313                   // fused tiles per batch: ceil(5000/16)
#define SFP 124                  // padded sf row stride (bank-spread)
#define NMOM (B_ * H_ * NCH)     // 400 moment units
#define NF (B_ * GX)             // 626 fused units
#define GRID_MF (NMOM + NF)      // 1026 blocks

typedef float v2f __attribute__((ext_vector_type(2)));
__device__ __forceinline__ v2f vsplat(float x) { v2f r; r.x = x; r.y = x; return r; }

// monomial index tables; slot 4 is the constant-1 slot.
__constant__ int TD[NM] = {4, 0,1,2,3, 0,0,0,0,1,1,1,2,2,3,
                           0,0,0,0,0,0,0,0,0,0,1,1,1,1,1,1,2,2,2,3};
__constant__ int TE[NM] = {4, 4,4,4,4, 0,1,2,3,1,2,3,2,3,3,
                           0,0,0,0,1,1,1,2,2,3,1,1,1,2,2,3,2,2,3,3};
__constant__ int TF[NM] = {4, 4,4,4,4, 4,4,4,4,4,4,4,4,4,4,
                           0,1,2,3,1,2,3,2,3,3,1,2,3,2,3,3,2,3,3,3};

// 10000^(-expo), even e: e/20, odd e: (e+1)/20 -- compile-time constants,
// correctly rounded (== libm pow to <=1 ulp).
__constant__ double FACT[E_] = {
    1.0,
    0.3981071705534972,    0.3981071705534972,
    0.15848931924611134,   0.15848931924611134,
    0.06309573444801933,   0.06309573444801933,
    0.025118864315095794,  0.025118864315095794,
    0.01,                  0.01,
    0.003981071705534973,  0.003981071705534973,
    0.0015848931924611134, 0.0015848931924611134,
    0.000630957344480193,  0.000630957344480193,
    0.00025118864315095795,0.00025118864315095795,
    0.0001};

__device__ __forceinline__ void mono36(const float x[4], float m[36]) {
  int idx = 0;
  m[idx++] = 1.f;
#pragma unroll
  for (int d = 0; d < 4; d++) m[idx++] = x[d];
#pragma unroll
  for (int d = 0; d < 4; d++)
#pragma unroll
    for (int e = d; e < 4; e++) m[idx++] = x[d] * x[e];
#pragma unroll
  for (int d = 0; d < 4; d++)
#pragma unroll
    for (int e = d; e < 4; e++)
#pragma unroll
      for (int f = e; f < 4; f++) m[idx++] = x[d] * x[e] * x[f];
  m[35] = 0.f;
}

__device__ __forceinline__ void qcoef(float* mq) {
  const float S = 1.f / 6.f;
  mq[5]  *= 0.5f; mq[9]  *= 0.5f; mq[12] *= 0.5f; mq[14] *= 0.5f;
  mq[15] *= S;    mq[25] *= S;    mq[31] *= S;    mq[34] *= S;
  mq[16] *= 0.5f; mq[17] *= 0.5f; mq[18] *= 0.5f; mq[19] *= 0.5f;
  mq[22] *= 0.5f; mq[24] *= 0.5f; mq[26] *= 0.5f; mq[27] *= 0.5f;
  mq[28] *= 0.5f; mq[30] *= 0.5f; mq[32] *= 0.5f; mq[33] *= 0.5f;
}

#define DOT20G(res, W, row, vec)                                     \
  {                                                                  \
    const float4* Wr = (const float4*)((W) + (row) * 20);            \
    float c0 = 0.f, c1 = 0.f, c2 = 0.f, c3 = 0.f;                    \
    _Pragma("unroll") for (int g5 = 0; g5 < 5; g5++) {               \
      float4 w4 = Wr[g5];                                            \
      c0 += w4.x * vec[g5 * 4 + 0];                                  \
      c1 += w4.y * vec[g5 * 4 + 1];                                  \
      c2 += w4.z * vec[g5 * 4 + 2];                                  \
      c3 += w4.w * vec[g5 * 4 + 3];                                  \
    }                                                                \
    res += (c0 + c1) + (c2 + c3);                                    \
  }

#define DOT40G(res, W, row, vec)                                     \
  {                                                                  \
    const float4* Wr = (const float4*)((W) + (row) * 40);            \
    float c0 = 0.f, c1 = 0.f, c2 = 0.f, c3 = 0.f;                    \
    _Pragma("unroll") for (int g5 = 0; g5 < 10; g5++) {              \
      float4 w4 = Wr[g5];                                            \
      c0 += w4.x * vec[g5 * 4 + 0];                                  \
      c1 += w4.y * vec[g5 * 4 + 1];                                  \
      c2 += w4.z * vec[g5 * 4 + 2];                                  \
      c3 += w4.w * vec[g5 * 4 + 3];                                  \
    }                                                                \
    res += (c0 + c1) + (c2 + c3);                                    \
  }

// ---------------------------------------------------------------------------
// Kernel 1: conv embed + PE (FACT table, double sincos); zeroes all 4 M.
// One (b,l,e) per thread -- proven shape.
// ---------------------------------------------------------------------------
__global__ __launch_bounds__(256) void conv_pe_kernel(
    const float* __restrict__ x, const float* __restrict__ w,
    float* __restrict__ hbuf, float* __restrict__ Mall) {
  int tid = blockIdx.x * 256 + threadIdx.x;
  if (tid < 4 * MLAYER) Mall[tid] = 0.f;
  if (tid >= B_ * L_ * E_) return;
  int e = tid % E_;
  int bl = tid / E_;
  int b = bl / L_, l = bl % L_;

  const float* xr = x + b * L_;
  const float* wr = w + e * K_;
  float a0 = 0.f, a1 = 0.f;
#pragma unroll
  for (int k = 0; k < K_; k += 2) {
    int i0 = l + k - PAD_, i1 = i0 + 1;
    float x0 = (i0 >= 0 && i0 < L_) ? xr[i0] : 0.f;
    float x1 = (i1 >= 0 && i1 < L_) ? xr[i1] : 0.f;
    a0 += x0 * wr[k];
    a1 += x1 * wr[k + 1];
  }
  double arg = (double)l * FACT[e];
  float pe = (e & 1) ? (float)cos(arg) : (float)sin(arg);
  hbuf[bl * E_ + e] = (a0 + a1) + pe;
}

// ---------------------------------------------------------------------------
// Merged moment+fused dispatch. 1026 blocks x 256 thr. Each block claims a
// ticket: first 400 claimants run the proven moment body (producers, never
// wait); the other 626 run the proven fused body after spinning on g_done
// (RELAXED poll + one ACQUIRE). Deadlock-free with NO dispatch-order
// assumption: whichever blocks run first BECOME producers. Counters
// self-reset (last fused block zeroes them) -> iteration/replay safe.
// ---------------------------------------------------------------------------
__device__ int g_ticket = 0;
__device__ int g_done = 0;
__device__ int g_fd = 0;

union SMEMU {
  float kvs[10][ACH + 2];  // moment staging (5.2 KB)
  struct {
    float4 so4[16][7];     // [p16][head], padded
    float stv[16 * 20];    // attn-out rows
    union {
      struct { float sf[16 * SFP]; float stv2[16 * 20]; } d;
      float dec[16 * 101]; // decoder scratch (LAST only)
    } u;
  } f;                     // 12.3 KB
};

template <int LAST>
__global__ __launch_bounds__(256) void mf_kernel(
    float* __restrict__ hbuf,
    const float* __restrict__ Wk, const float* __restrict__ Wv,
    float* __restrict__ M, const float* __restrict__ Wq,
    const float* __restrict__ Wc, const float* __restrict__ bc,
    const float* __restrict__ lnAg, const float* __restrict__ lnAb,
    const float* __restrict__ W1, const float* __restrict__ b1,
    const float* __restrict__ W2, const float* __restrict__ b2,
    const float* __restrict__ lnBg, const float* __restrict__ lnBb,
    const float* __restrict__ f1w, const float* __restrict__ f1b,
    const float* __restrict__ f2w, const float* __restrict__ f2b,
    const float* __restrict__ f3w, const float* __restrict__ f3b,
    const float* __restrict__ f4w, const float* __restrict__ f4b,
    float* __restrict__ out) {
  __shared__ SMEMU S;
  __shared__ int s_unit;
  int tid = threadIdx.x;
  if (tid == 0) {
    s_unit = __hip_atomic_fetch_add(&g_ticket, 1, __ATOMIC_RELAXED,
                                    __HIP_MEMORY_SCOPE_AGENT);
  }
  __syncthreads();
  const int unit = s_unit;

  if (unit < NMOM) {
    // ================= moment producer (proven 192-thr body) ==============
    int bh = unit / NCH;
    int chunk = unit % NCH;
    int b = bh / H_, hh = bh % H_;

    if (tid < ACH) {
      float wk[16], wv[16];
#pragma unroll
      for (int i = 0; i < 16; i++) { wk[i] = Wk[i]; wv[i] = Wv[i]; }
      int j = chunk * ACH + tid;
      bool valid = j < L_;
      int jc = valid ? j : (L_ - 1);
      float4 s4 = *(const float4*)(hbuf + (b * L_ + jc) * E_ + hh * 4);
      float vm = valid ? 1.f : 0.f;
      int t = tid;
      S.kvs[0][t] = wk[0] * s4.x + wk[1] * s4.y + wk[2] * s4.z + wk[3] * s4.w;
      S.kvs[1][t] = wk[4] * s4.x + wk[5] * s4.y + wk[6] * s4.z + wk[7] * s4.w;
      S.kvs[2][t] = wk[8] * s4.x + wk[9] * s4.y + wk[10] * s4.z + wk[11] * s4.w;
      S.kvs[3][t] = wk[12] * s4.x + wk[13] * s4.y + wk[14] * s4.z + wk[15] * s4.w;
      S.kvs[4][t] = 1.f;
      S.kvs[5][t] = (wv[0] * s4.x + wv[1] * s4.y + wv[2] * s4.z + wv[3] * s4.w) * vm;
      S.kvs[6][t] = (wv[4] * s4.x + wv[5] * s4.y + wv[6] * s4.z + wv[7] * s4.w) * vm;
      S.kvs[7][t] = (wv[8] * s4.x + wv[9] * s4.y + wv[10] * s4.z + wv[11] * s4.w) * vm;
      S.kvs[8][t] = (wv[12] * s4.x + wv[13] * s4.y + wv[14] * s4.z + wv[15] * s4.w) * vm;
      S.kvs[9][t] = vm;
    }
    __syncthreads();

    if (tid < NM * 5) {
      int m = tid / 5, c = tid % 5;
      int sd = TD[m], se = TE[m], sf = TF[m], sv = 5 + c;
      v2f acc = vsplat(0.f);
#pragma unroll 4
      for (int j = 0; j < ACH; j += 2) {
        v2f a = *(const v2f*)&S.kvs[sd][j];
        v2f bq = *(const v2f*)&S.kvs[se][j];
        v2f cq = *(const v2f*)&S.kvs[sf][j];
        v2f vv = *(const v2f*)&S.kvs[sv][j];
        acc += a * bq * cq * vv;
      }
      atomicAdd(&M[bh * MST2 + c * 36 + m], acc.x + acc.y);
    }
    __syncthreads();  // all atomics issued & drained (barrier waits vmcnt)
    if (tid == 0) {
      __threadfence();  // release: M atomics visible before done-signal
      __hip_atomic_fetch_add(&g_done, 1, __ATOMIC_RELEASE,
                             __HIP_MEMORY_SCOPE_AGENT);
    }
    return;
  }

  // ================== fused consumer (proven R7 256-thr body) =============
  int fbid = unit - NMOM;
  int b = fbid / GX;
  int tile = fbid % GX;
  int p16 = tid & 15;
  int part = tid >> 4;  // 0..15
  int l = tile * 16 + p16;
  bool act = l < L_;
  int lc = act ? l : L_ - 1;
  int pos = b * L_ + lc;

  // wait for all 400 moment producers (RELAXED poll; one ACQUIRE on exit)
  if (tid == 0) {
    while (__hip_atomic_load(&g_done, __ATOMIC_RELAXED,
                             __HIP_MEMORY_SCOPE_AGENT) < NMOM) {
      __builtin_amdgcn_s_sleep(4);
    }
    (void)__hip_atomic_load(&g_done, __ATOMIC_ACQUIRE,
                            __HIP_MEMORY_SCOPE_AGENT);
  }
  __syncthreads();

  // residual vector (constant-indexed only -> stays in VGPRs)
  float hv[E_];
#pragma unroll
  for (int e4 = 0; e4 < 5; e4++) {
    float4 h4 = *(const float4*)(hbuf + pos * E_ + e4 * 4);
    hv[e4 * 4 + 0] = h4.x; hv[e4 * 4 + 1] = h4.y;
    hv[e4 * 4 + 2] = h4.z; hv[e4 * 4 + 3] = h4.w;
  }

  // ---- A: attention eval, head = part (parts 5-15 idle; stage is short) ----
  if (part < H_) {
    float q[4];
    {
      float4 qsrc = *(const float4*)(hbuf + pos * E_ + part * 4);
#pragma unroll
      for (int d = 0; d < 4; d++) {
        q[d] = (Wq[d * 4 + 0] * qsrc.x + Wq[d * 4 + 1] * qsrc.y +
                Wq[d * 4 + 2] * qsrc.z + Wq[d * 4 + 3] * qsrc.w) *
               SCALE;
      }
    }
    float mq[36];
    mono36(q, mq);
    qcoef(mq);
    const float* Mb = M + (b * H_ + part) * MST2;
    float oc[5];
#pragma unroll
    for (int c = 0; c < 5; c++) {
      const float4* Mr = (const float4*)(Mb + c * 36);
      float a0 = 0.f, a1 = 0.f, a2 = 0.f, a3 = 0.f;
#pragma unroll
      for (int g = 0; g < 9; g++) {
        float4 w4 = Mr[g];
        a0 += w4.x * mq[g * 4 + 0];
        a1 += w4.y * mq[g * 4 + 1];
        a2 += w4.z * mq[g * 4 + 2];
        a3 += w4.w * mq[g * 4 + 3];
      }
      oc[c] = (a0 + a1) + (a2 + a3);
    }
    float inv = 1.f / oc[4];
    S.f.so4[p16][part] =
        make_float4(oc[0] * inv, oc[1] * inv, oc[2] * inv, oc[3] * inv);
  }
  __syncthreads();

  // ---- B: Wc rows part (+ part+16 for part<4) -> stv ----
  {
    float o[E_];
#pragma unroll
    for (int hh = 0; hh < H_; hh++) {
      float4 o4 = S.f.so4[p16][hh];
      o[hh * 4 + 0] = o4.x; o[hh * 4 + 1] = o4.y;
      o[hh * 4 + 2] = o4.z; o[hh * 4 + 3] = o4.w;
    }
    {
      int row = part;
      float acc = bc[row];
      DOT20G(acc, Wc, row, o);
      S.f.stv[p16 * 20 + row] = acc;
    }
    if (part < 4) {
      int row = part + 16;
      float acc = bc[row];
      DOT20G(acc, Wc, row, o);
      S.f.stv[p16 * 20 + row] = acc;
    }
  }
  __syncthreads();

  // ---- C: add residual, LN_A (redundant per thread) ----
  float tv[E_];
#pragma unroll
  for (int e4 = 0; e4 < 5; e4++) {
    float4 t4 = *(const float4*)(S.f.stv + p16 * 20 + e4 * 4);
    tv[e4 * 4 + 0] = t4.x + hv[e4 * 4 + 0];
    tv[e4 * 4 + 1] = t4.y + hv[e4 * 4 + 1];
    tv[e4 * 4 + 2] = t4.z + hv[e4 * 4 + 2];
    tv[e4 * 4 + 3] = t4.w + hv[e4 * 4 + 3];
  }
  float mu = 0.f;
#pragma unroll
  for (int e = 0; e < E_; e++) mu += tv[e];
  mu *= (1.f / E_);
  float var = 0.f;
#pragma unroll
  for (int e = 0; e < E_; e++) { float d = tv[e] - mu; var += d * d; }
  var *= (1.f / E_);
  float rs = rsqrtf(var + 1e-5f);
  float h1[E_];
#pragma unroll
  for (int e = 0; e < E_; e++) h1[e] = (tv[e] - mu) * rs * lnAg[e] + lnAb[e];

  // ---- D1: FFN first layer, rows j = part + 16k -> sf ----
#pragma unroll
  for (int k = 0; k < 8; k++) {
    int j = part + 16 * k;
    if (j < FF_) {
      float f = b1[j];
      DOT20G(f, W1, j, h1);
      S.f.u.d.sf[p16 * SFP + j] = fmaxf(f, 0.f);
    }
  }
  __syncthreads();

  // ---- D2: FFN second layer, output e = part (+ part+16 for part<4),
  //      W2 natural row layout [e][120] ----
  {
    const float4* fr = (const float4*)(S.f.u.d.sf + p16 * SFP);
    {
      int e = part;
      const float4* Wr = (const float4*)(W2 + e * FF_);
      float c0 = 0.f, c1 = 0.f, c2 = 0.f, c3 = 0.f;
#pragma unroll
      for (int g = 0; g < 30; g++) {
        float4 w4 = Wr[g];
        float4 f4 = fr[g];
        c0 += w4.x * f4.x; c1 += w4.y * f4.y;
        c2 += w4.z * f4.z; c3 += w4.w * f4.w;
      }
      S.f.u.d.stv2[p16 * 20 + e] = b2[e] + (c0 + c1) + (c2 + c3);
    }
    if (part < 4) {
      int e = part + 16;
      const float4* Wr = (const float4*)(W2 + e * FF_);
      float c0 = 0.f, c1 = 0.f, c2 = 0.f, c3 = 0.f;
#pragma unroll
      for (int g = 0; g < 30; g++) {
        float4 w4 = Wr[g];
        float4 f4 = fr[g];
        c0 += w4.x * f4.x; c1 += w4.y * f4.y;
        c2 += w4.z * f4.z; c3 += w4.w * f4.w;
      }
      S.f.u.d.stv2[p16 * 20 + e] = b2[e] + (c0 + c1) + (c2 + c3);
    }
  }
  __syncthreads();

  // ---- E: + residual(h1), LN_B (redundant per thread) ----
  float g2[E_];
#pragma unroll
  for (int e4 = 0; e4 < 5; e4++) {
    float4 v4 = *(const float4*)(S.f.u.d.stv2 + p16 * 20 + e4 * 4);
    g2[e4 * 4 + 0] = v4.x + h1[e4 * 4 + 0];
    g2[e4 * 4 + 1] = v4.y + h1[e4 * 4 + 1];
    g2[e4 * 4 + 2] = v4.z + h1[e4 * 4 + 2];
    g2[e4 * 4 + 3] = v4.w + h1[e4 * 4 + 3];
  }
  float mu2 = 0.f;
#pragma unroll
  for (int e = 0; e < E_; e++) mu2 += g2[e];
  mu2 *= (1.f / E_);
  float var2 = 0.f;
#pragma unroll
  for (int e = 0; e < E_; e++) { float d = g2[e] - mu2; var2 += d * d; }
  var2 *= (1.f / E_);
  float rs2 = rsqrtf(var2 + 1e-5f);
  float hn[E_];
#pragma unroll
  for (int e = 0; e < E_; e++) hn[e] = (g2[e] - mu2) * rs2 * lnBg[e] + lnBb[e];

  if (!LAST) {
    if (act && part == 0) {
#pragma unroll
      for (int e4 = 0; e4 < 5; e4++) {
        *(float4*)(hbuf + pos * E_ + e4 * 4) =
            make_float4(hn[e4 * 4], hn[e4 * 4 + 1], hn[e4 * 4 + 2],
                        hn[e4 * 4 + 3]);
      }
    }
  } else {
    // dec overlays sf/stv2; D2/E LDS reads fenced by the sync above.
    __syncthreads();
#pragma unroll
    for (int k = 0; k < 3; k++) {
      int row = part + 16 * k;
      if (row < DEC_) {
        float a = f1b[row];
        DOT20G(a, f1w, row, hn);
        S.f.u.dec[p16 * 101 + row] = fmaxf(a, 0.f);
      }
    }
    __syncthreads();
    float d1[DEC_];
#pragma unroll
    for (int kk = 0; kk < DEC_; kk++) d1[kk] = S.f.u.dec[p16 * 101 + kk];
#pragma unroll
    for (int k = 0; k < 3; k++) {
      int row = part + 16 * k;
      if (row < DEC_) {
        float a = f2b[row];
        DOT40G(a, f2w, row, d1);
        S.f.u.dec[p16 * 101 + 40 + row] = fmaxf(a, 0.f);
      }
    }
    __syncthreads();
    float d2[DEC_];
#pragma unroll
    for (int kk = 0; kk < DEC_; kk++) d2[kk] = S.f.u.dec[p16 * 101 + 40 + kk];
    {
      float a = f3b[part];
      DOT40G(a, f3w, part, d2);
      S.f.u.dec[p16 * 101 + 80 + part] = fmaxf(a, 0.f);
    }
    if (part < 4) {
      int ee = part + 16;
      float a = f3b[ee];
      DOT40G(a, f3w, ee, d2);
      S.f.u.dec[p16 * 101 + 80 + ee] = fmaxf(a, 0.f);
    }
    __syncthreads();
    if (act && part == 0) {
      float z = f4b[0];
      const float* dv = S.f.u.dec + p16 * 101 + 80;
      DOT20G(z, f4w, 0, dv);
      out[pos] = 1.f / (1.f + __expf(-z));
    }
  }

  // ---- counter reset: last fused block zeroes ticket/done/fd ----
  __syncthreads();  // block fully done (incl. decoder LDS reads)
  if (tid == 0) {
    int f = __hip_atomic_fetch_add(&g_fd, 1, __ATOMIC_RELAXED,
                                   __HIP_MEMORY_SCOPE_AGENT);
    if (f == NF - 1) {
      __hip_atomic_store(&g_done, 0, __ATOMIC_RELAXED,
                         __HIP_MEMORY_SCOPE_AGENT);
      __hip_atomic_store(&g_ticket, 0, __ATOMIC_RELAXED,
                         __HIP_MEMORY_SCOPE_AGENT);
      __hip_atomic_store(&g_fd, 0, __ATOMIC_RELAXED,
                         __HIP_MEMORY_SCOPE_AGENT);
    }
  }
}

// ---------------------------------------------------------------------------
extern "C" void kernel_launch(void* const* d_in, const int* in_sizes, int n_in,
                              void* d_out, int out_size, void* d_ws,
                              size_t ws_size, hipStream_t stream) {
  const float* x    = (const float*)d_in[0];
  const float* cw   = (const float*)d_in[1];
  const float* Wv   = (const float*)d_in[2];
  const float* Wk   = (const float*)d_in[3];
  const float* Wq   = (const float*)d_in[4];
  const float* Wc   = (const float*)d_in[5];
  const float* bc   = (const float*)d_in[6];
  const float* lnAg = (const float*)d_in[7];
  const float* lnAb = (const float*)d_in[8];
  const float* W1   = (const float*)d_in[9];
  const float* b1   = (const float*)d_in[10];
  const float* W2   = (const float*)d_in[11];
  const float* b2   = (const float*)d_in[12];
  const float* lnBg = (const float*)d_in[13];
  const float* lnBb = (const float*)d_in[14];
  const float* f1w  = (const float*)d_in[15];
  const float* f1b  = (const float*)d_in[16];
  const float* f2w  = (const float*)d_in[17];
  const float* f2b  = (const float*)d_in[18];
  const float* f3w  = (const float*)d_in[19];
  const float* f3b  = (const float*)d_in[20];
  const float* f4w  = (const float*)d_in[21];
  const float* f4b  = (const float*)d_in[22];
  float* out = (float*)d_out;

  // ws floats: h 200000 | Mall 4*1800
  float* ws = (float*)d_ws;
  float* h = ws;
  float* Mall = ws + 200000;

  conv_pe_kernel<<<(B_ * L_ * E_ + 255) / 256, 256, 0, stream>>>(x, cw, h,
                                                                 Mall);

  for (int i = 0; i < 4; i++) {
    if (i < 3) {
      mf_kernel<0><<<GRID_MF, 256, 0, stream>>>(
          h, Wk + i * 16, Wv + i * 16, Mall + i * MLAYER, Wq + i * 16,
          Wc + i * 400, bc + i * 20, lnAg + i * 20, lnAb + i * 20,
          W1 + i * 2400, b1 + i * 120, W2 + i * 2400, b2 + i * 20,
          lnBg + i * 20, lnBb + i * 20, f1w, f1b, f2w, f2b, f3w, f3b,
          f4w, f4b, out);
    } else {
      mf_kernel<1><<<GRID_MF, 256, 0, stream>>>(
          h, Wk + i * 16, Wv + i * 16, Mall + i * MLAYER, Wq + i * 16,
          Wc + i * 400, bc + i * 20, lnAg + i * 20, lnAb + i * 20,
          W1 + i * 2400, b1 + i * 120, W2 + i * 2400, b2 + i * 20,
          lnBg + i * 20, lnBb + i * 20, f1w, f1b, f2w, f2b, f3w, f3b,
          f4w, f4b, out);
    }
  }
}